// Round 20
// baseline (455.907 us; speedup 1.0000x reference)
//
#include <hip/hip_runtime.h>
#include <math.h>
#include <stdint.h>

#define H_   1024
#define HR_  256
#define DI_  2048
#define NS_  16
#define KC_  4
#define DTR_ 64
#define B_   4
#define L_   1024
#define ROWS (B_*L_)   // 4096
#define H3_  3072
#define NCH_ 32        // scan chunks
#define CL_  32        // chunk length
#define CLT_ 8         // conv rows per thread

typedef short bf16x8 __attribute__((ext_vector_type(8)));
typedef float f32x4  __attribute__((ext_vector_type(4)));

#if __has_builtin(__builtin_amdgcn_exp2f)
#define EXP2(x) __builtin_amdgcn_exp2f(x)
#else
#define EXP2(x) __expf((x) * 0.6931471805599453f)
#endif
#define LOG2E 1.4426950408889634f

__device__ __forceinline__ float silu_f(float v) { return v / (1.f + __expf(-v)); }

__device__ __forceinline__ uint32_t pack_bf16_2(float a, float b) {
    uint32_t ua = __float_as_uint(a);
    uint32_t ub = __float_as_uint(b);
    uint32_t ra = (ua + 0x7FFFu + ((ua >> 16) & 1u)) >> 16;
    uint32_t rb = (ub + 0x7FFFu + ((ub >> 16) & 1u)) >> 16;
    return ra | (rb << 16);
}
__device__ __forceinline__ unsigned short cvt_bf16(float a) {
    uint32_t ua = __float_as_uint(a);
    return (unsigned short)((ua + 0x7FFFu + ((ua >> 16) & 1u)) >> 16);
}
__device__ __forceinline__ float bf16_to_f(unsigned short u) {
    return __uint_as_float(((uint32_t)u) << 16);
}

// async global->LDS, 16B per lane: LDS dest = wave-uniform base + lane*16
__device__ __forceinline__ void gload16(const short* g, short* l) {
    __builtin_amdgcn_global_load_lds(
        (const __attribute__((address_space(1))) void*)g,
        (__attribute__((address_space(3))) void*)l, 16, 0, 0);
}

// ---------------------------------------------------------------------------
// Transposed bf16 weight arena offsets (shorts). Wt layout: [Npad][K]
// ---------------------------------------------------------------------------
#define TW_HGDFR 0ull        // [512][1024]: rows 0-255 hgd_w1, 256-511 fr_w
#define TW_HGD2  524288ull   // [1024][256]
#define TW_INPJ  786432ull   // [4096][1024]
#define TW_XPJ   4980736ull  // [128][2048] (zero-padded from 96)
#define TW_DTPJ  5242880ull  // [2048][64]
#define TW_OPJ   5373952ull  // [1024][2048]
#define TW_FM    7471104ull  // [256][1024]
#define TW_FF    7733248ull  // [1024][256]
#define TWT      7995392ull

// ---------------------------------------------------------------------------
// K0: transpose+convert weights: W[K][N] f32 -> Wt[Npad][K] bf16
// ---------------------------------------------------------------------------
__global__ __launch_bounds__(256) void wtrans_kernel(
    const float* __restrict__ s0, const float* __restrict__ s1,
    const float* __restrict__ s2, const float* __restrict__ s3,
    const float* __restrict__ s4, const float* __restrict__ s5,
    const float* __restrict__ s6, const float* __restrict__ s7,
    const float* __restrict__ s8, short* __restrict__ wt)
{
    int bid = blockIdx.x;
    const float* src; short* dst; int K, N, rel;
    if      (bid < 256)  { src = s0; dst = wt + TW_HGDFR;          K = 1024; N = 256;  rel = bid; }
    else if (bid < 512)  { src = s1; dst = wt + TW_HGDFR + 262144; K = 1024; N = 256;  rel = bid - 256; }
    else if (bid < 768)  { src = s2; dst = wt + TW_HGD2;           K = 256;  N = 1024; rel = bid - 512; }
    else if (bid < 4864) { src = s3; dst = wt + TW_INPJ;           K = 1024; N = 4096; rel = bid - 768; }
    else if (bid < 5120) { src = s4; dst = wt + TW_XPJ;            K = 2048; N = 96;   rel = bid - 4864; }
    else if (bid < 5248) { src = s5; dst = wt + TW_DTPJ;           K = 64;   N = 2048; rel = bid - 5120; }
    else if (bid < 7296) { src = s6; dst = wt + TW_OPJ;            K = 2048; N = 1024; rel = bid - 5248; }
    else if (bid < 7552) { src = s7; dst = wt + TW_FM;             K = 1024; N = 256;  rel = bid - 7296; }
    else                 { src = s8; dst = wt + TW_FF;             K = 256;  N = 1024; rel = bid - 7552; }
    int tkc = K >> 5;
    int tk = rel % tkc, tn = rel / tkc;

    __shared__ float ld[32][33];
    int tx = threadIdx.x & 7, ty = threadIdx.x >> 3;
    int kk = tk * 32 + ty, nn = tn * 32 + tx * 4;
    float4 v = make_float4(0.f, 0.f, 0.f, 0.f);
    if (nn < N) v = *(const float4*)&src[(size_t)kk * N + nn];
    ld[ty][tx * 4 + 0] = v.x; ld[ty][tx * 4 + 1] = v.y;
    ld[ty][tx * 4 + 2] = v.z; ld[ty][tx * 4 + 3] = v.w;
    __syncthreads();
    int nn2 = tn * 32 + ty, kk2 = tk * 32 + tx * 4;
    float a0 = ld[tx * 4 + 0][ty], a1 = ld[tx * 4 + 1][ty];
    float a2 = ld[tx * 4 + 2][ty], a3 = ld[tx * 4 + 3][ty];
    uint2 p = { pack_bf16_2(a0, a1), pack_bf16_2(a2, a3) };
    *(uint2*)&dst[(size_t)nn2 * K + kk2] = p;
}

// ---------------------------------------------------------------------------
// K0b: conv weight transpose
// ---------------------------------------------------------------------------
__global__ __launch_bounds__(256) void cwt_kernel(
    const float* __restrict__ conv_w, float* __restrict__ cwt)
{
    int d = blockIdx.x * 256 + threadIdx.x;
    float4 v = *(const float4*)&conv_w[d * KC_];
    cwt[0 * DI_ + d] = v.x;
    cwt[1 * DI_ + d] = v.y;
    cwt[2 * DI_ + d] = v.z;
    cwt[3 * DI_ + d] = v.w;
}

// ---------------------------------------------------------------------------
// K1a/b: ada = silu(t) @ ada_w + ada_b  (splitK=32)
// ---------------------------------------------------------------------------
__global__ __launch_bounds__(256) void ada_part_kernel(
    const float* __restrict__ t, const float* __restrict__ ada_w,
    float* __restrict__ part)
{
    int col = blockIdx.x * 1024 + threadIdx.x * 4;
    int b = blockIdx.y, z = blockIdx.z;
    __shared__ float st[32];
    if (threadIdx.x < 32) {
        float v = t[b * H_ + z * 32 + threadIdx.x];
        st[threadIdx.x] = silu_f(v);
    }
    __syncthreads();
    float4 acc = make_float4(0.f, 0.f, 0.f, 0.f);
    const float* w = ada_w + (size_t)(z * 32) * H3_ + col;
    #pragma unroll
    for (int k = 0; k < 32; ++k) {
        float4 wv = *(const float4*)(w + (size_t)k * H3_);
        float s = st[k];
        acc.x = fmaf(s, wv.x, acc.x);
        acc.y = fmaf(s, wv.y, acc.y);
        acc.z = fmaf(s, wv.z, acc.z);
        acc.w = fmaf(s, wv.w, acc.w);
    }
    *(float4*)&part[((size_t)z * B_ + b) * H3_ + col] = acc;
}

__global__ __launch_bounds__(256) void ada_red_kernel(
    const float* __restrict__ part, const float* __restrict__ ada_b,
    float* __restrict__ ada)
{
    int i = (blockIdx.x * 256 + threadIdx.x) * 4;
    int b = i / H3_, col = i - b * H3_;
    float4 s = make_float4(0.f, 0.f, 0.f, 0.f);
    #pragma unroll
    for (int z = 0; z < 32; ++z) {
        float4 p = *(const float4*)&part[((size_t)z * B_ + b) * H3_ + col];
        s.x += p.x; s.y += p.y; s.z += p.z; s.w += p.w;
    }
    float4 bv = *(const float4*)&ada_b[col];
    s.x += bv.x; s.y += bv.y; s.z += bv.z; s.w += bv.w;
    *(float4*)&ada[(size_t)b * H3_ + col] = s;
}

// ---------------------------------------------------------------------------
// K2: x1 = LN(x) * (1+scale) + shift  -> bf16
// ---------------------------------------------------------------------------
__global__ __launch_bounds__(256) void ln_mod_kernel(
    const float* __restrict__ x, const float* __restrict__ ada,
    short* __restrict__ x1b)
{
    int row = blockIdx.x;
    int b   = row >> 10;
    const float* xr = x + (size_t)row * H_;
    float4 v = ((const float4*)xr)[threadIdx.x];
    float s  = v.x + v.y + v.z + v.w;
    float s2 = v.x*v.x + v.y*v.y + v.z*v.z + v.w*v.w;

    __shared__ float red[8];
    int wave = threadIdx.x >> 6, lane = threadIdx.x & 63;
    #pragma unroll
    for (int off = 32; off; off >>= 1) {
        s  += __shfl_down(s,  off);
        s2 += __shfl_down(s2, off);
    }
    if (lane == 0) { red[wave] = s; red[4 + wave] = s2; }
    __syncthreads();
    float ts  = red[0] + red[1] + red[2] + red[3];
    float ts2 = red[4] + red[5] + red[6] + red[7];
    float mu  = ts  * (1.f / H_);
    float var = ts2 * (1.f / H_) - mu * mu;
    float inv = rsqrtf(var + 1e-6f);

    const float* sh = ada + b * H3_;
    int i = threadIdx.x * 4;
    float4 sh4 = *(const float4*)&sh[i];
    float4 sc4 = *(const float4*)&sh[H_ + i];
    float ox = (v.x - mu) * inv * (1.f + sc4.x) + sh4.x;
    float oy = (v.y - mu) * inv * (1.f + sc4.y) + sh4.y;
    float oz = (v.z - mu) * inv * (1.f + sc4.z) + sh4.z;
    float ow = (v.w - mu) * inv * (1.f + sc4.w) + sh4.w;
    uint2 p = { pack_bf16_2(ox, oy), pack_bf16_2(oz, ow) };
    *(uint2*)(x1b + (size_t)row * H_ + i) = p;
}

// ---------------------------------------------------------------------------
// K3a: gemm128 — 128x128, BK=32, 4 waves, 3-buf counted vmcnt.
// ACT: 0 none, 2 softplus->Cb, 4 E0+alpha*v->C, 6 hgd1|fr split
// ---------------------------------------------------------------------------
template<int ACT, bool SPLITK>
__global__ __launch_bounds__(256) void gemm128(
    const short* __restrict__ A, int lda,
    const short* __restrict__ Wt, int ldw,
    const float* __restrict__ bias,
    float* __restrict__ C, short* __restrict__ Cb, short* __restrict__ Cb2,
    int ldc, int M, int N, int K,
    const float* __restrict__ E0, const float* __restrict__ E1)
{
    __shared__ short As[3][4096];
    __shared__ short Bs[3][4096];
    int tid  = threadIdx.x;
    int lane = tid & 63, wv = tid >> 6, wm = wv >> 1, wn = wv & 1;
    int n0 = blockIdx.x * 128;
    int m0 = blockIdx.y * 128;

    if (SPLITK) {
        int z = blockIdx.z;
        A  += (size_t)z * K;
        Wt += (size_t)z * K;
        C  += (size_t)z * M * N;
    }

    int r = lane & 15, g = lane >> 4;
    int sA = wv * 2;
    const short* ga0 = A  + (size_t)(m0 + sA * 16 + r) * lda + g * 8;
    const short* ga1 = ga0 + (size_t)16 * lda;
    const short* gb0 = Wt + (size_t)(n0 + sA * 16 + r) * ldw + g * 8;
    const short* gb1 = gb0 + (size_t)16 * ldw;

    f32x4 acc[4][4];
    #pragma unroll
    for (int i = 0; i < 4; ++i)
        #pragma unroll
        for (int j = 0; j < 4; ++j) {
            acc[i][j][0] = 0.f; acc[i][j][1] = 0.f;
            acc[i][j][2] = 0.f; acc[i][j][3] = 0.f;
        }

    #define STAGE(buf, koff)                                    \
        do {                                                    \
            gload16(ga0 + (koff), &As[buf][sA * 512]);          \
            gload16(ga1 + (koff), &As[buf][sA * 512 + 512]);    \
            gload16(gb0 + (koff), &Bs[buf][sA * 512]);          \
            gload16(gb1 + (koff), &Bs[buf][sA * 512 + 512]);    \
        } while (0)

    #define COMPUTE(buf)                                                          \
        do {                                                                      \
            bf16x8 af[4], bfr[4];                                                 \
            _Pragma("unroll")                                                     \
            for (int i = 0; i < 4; ++i)                                           \
                af[i] = *(const bf16x8*)&As[buf][(wm * 4 + i) * 512 + lane * 8];  \
            _Pragma("unroll")                                                     \
            for (int j = 0; j < 4; ++j)                                           \
                bfr[j] = *(const bf16x8*)&Bs[buf][(wn * 4 + j) * 512 + lane * 8]; \
            _Pragma("unroll")                                                     \
            for (int i = 0; i < 4; ++i)                                           \
                _Pragma("unroll")                                                 \
                for (int j = 0; j < 4; ++j)                                       \
                    acc[i][j] = __builtin_amdgcn_mfma_f32_16x16x32_bf16(          \
                        af[i], bfr[j], acc[i][j], 0, 0, 0);                       \
        } while (0)

    int T = K >> 5;
    STAGE(0, 0);
    if (T > 1) STAGE(1, 32);
    for (int t = 0; t < T; ++t) {
        if (t + 1 < T) asm volatile("s_waitcnt vmcnt(4)" ::: "memory");
        else           asm volatile("s_waitcnt vmcnt(0)" ::: "memory");
        __builtin_amdgcn_s_barrier();
        if (t + 2 < T) STAGE((t + 2) % 3, (t + 2) * 32);
        COMPUTE(t % 3);
    }
    #undef STAGE
    #undef COMPUTE

    #pragma unroll
    for (int i = 0; i < 4; ++i) {
        int mb = m0 + wm * 64 + i * 16 + ((lane >> 4) << 2);
        #pragma unroll
        for (int j = 0; j < 4; ++j) {
            int n = n0 + wn * 64 + j * 16 + (lane & 15);
            if (n < N) {
                float bv;
                if (ACT == 6) bv = (n < 256) ? bias[n] : E0[n - 256];
                else          bv = bias ? bias[n] : 0.f;
                #pragma unroll
                for (int rr = 0; rr < 4; ++rr) {
                    int m = mb + rr;
                    float v = acc[i][j][rr] + bv;
                    size_t ci = (size_t)m * ldc + n;
                    if (ACT == 6) {
                        float sv = silu_f(v);
                        if (n < 256) Cb[(size_t)m * 256 + n]        = (short)cvt_bf16(sv);
                        else         Cb2[(size_t)m * 256 + (n-256)] = (short)cvt_bf16(sv);
                    } else {
                        if (ACT == 2) v = (v > 20.f) ? v : log1pf(__expf(v));
                        else if (ACT == 4) {
                            int bb = m >> 10;
                            v = E0[ci] + E1[bb * H3_ + 2 * H_ + n] * v;
                        }
                        if (C)  C[ci]  = v;
                        if (Cb) Cb[ci] = (short)cvt_bf16(v);
                    }
                }
            }
        }
    }
}

// ---------------------------------------------------------------------------
// K3b: gemm256 — 256x256, BK=32, 8 waves, 3-buf counted vmcnt, 96 KB LDS.
// ACT: 5 in_proj split -> Cb arena; 8 bf16 splitK partials -> Cb + z*M*N
// ---------------------------------------------------------------------------
template<int ACT, bool SPLITK>
__global__ __launch_bounds__(512) void gemm256(
    const short* __restrict__ A, int lda,
    const short* __restrict__ Wt, int ldw,
    short* __restrict__ Cb, int ldc, int M, int N, int K)
{
    extern __shared__ short lds[];            // As: 3*8192, Bs: 3*8192
    short* Asb = lds;
    short* Bsb = lds + 24576;
    int tid  = threadIdx.x;
    int lane = tid & 63, wv = tid >> 6;
    int wm = wv >> 2, wn = wv & 3;
    int n0 = blockIdx.x * 256;
    int m0 = blockIdx.y * 256;

    if (SPLITK) {
        int z = blockIdx.z;
        A  += (size_t)z * K;
        Wt += (size_t)z * K;
        Cb += (size_t)z * M * N;
    }

    int r = lane & 15, g = lane >> 4;
    int sA = wv * 2;
    const short* ga0 = A  + (size_t)(m0 + sA * 16 + r) * lda + g * 8;
    const short* ga1 = ga0 + (size_t)16 * lda;
    const short* gb0 = Wt + (size_t)(n0 + sA * 16 + r) * ldw + g * 8;
    const short* gb1 = gb0 + (size_t)16 * ldw;

    f32x4 acc[8][4];
    #pragma unroll
    for (int i = 0; i < 8; ++i)
        #pragma unroll
        for (int j = 0; j < 4; ++j) {
            acc[i][j][0] = 0.f; acc[i][j][1] = 0.f;
            acc[i][j][2] = 0.f; acc[i][j][3] = 0.f;
        }

    #define STAGE2(buf, koff)                                       \
        do {                                                        \
            gload16(ga0 + (koff), &Asb[(buf) * 8192 + sA * 512]);   \
            gload16(ga1 + (koff), &Asb[(buf) * 8192 + sA * 512 + 512]); \
            gload16(gb0 + (koff), &Bsb[(buf) * 8192 + sA * 512]);   \
            gload16(gb1 + (koff), &Bsb[(buf) * 8192 + sA * 512 + 512]); \
        } while (0)

    int T = K >> 5;
    STAGE2(0, 0);
    if (T > 1) STAGE2(1, 32);
    for (int t = 0; t < T; ++t) {
        if (t + 1 < T) asm volatile("s_waitcnt vmcnt(4)" ::: "memory");
        else           asm volatile("s_waitcnt vmcnt(0)" ::: "memory");
        __builtin_amdgcn_s_barrier();
        if (t + 2 < T) STAGE2((t + 2) % 3, (t + 2) * 32);
        {
            int buf = t % 3;
            bf16x8 af[8], bfr[4];
            #pragma unroll
            for (int i = 0; i < 8; ++i)
                af[i] = *(const bf16x8*)&Asb[buf * 8192 + (wm * 8 + i) * 512 + lane * 8];
            #pragma unroll
            for (int j = 0; j < 4; ++j)
                bfr[j] = *(const bf16x8*)&Bsb[buf * 8192 + (wn * 4 + j) * 512 + lane * 8];
            __builtin_amdgcn_s_setprio(1);
            #pragma unroll
            for (int i = 0; i < 8; ++i)
                #pragma unroll
                for (int j = 0; j < 4; ++j)
                    acc[i][j] = __builtin_amdgcn_mfma_f32_16x16x32_bf16(
                        af[i], bfr[j], acc[i][j], 0, 0, 0);
            __builtin_amdgcn_s_setprio(0);
        }
    }
    #undef STAGE2

    #pragma unroll
    for (int i = 0; i < 8; ++i) {
        int mb = m0 + wm * 128 + i * 16 + ((lane >> 4) << 2);
        #pragma unroll
        for (int j = 0; j < 4; ++j) {
            int n = n0 + wn * 64 + j * 16 + (lane & 15);
            #pragma unroll
            for (int rr = 0; rr < 4; ++rr) {
                int m = mb + rr;
                float v = acc[i][j][rr];
                if (ACT == 5) {
                    size_t idx = (n < DI_) ? ((size_t)m * DI_ + n)
                                           : ((size_t)ROWS * DI_ + (size_t)m * DI_ + (n - DI_));
                    Cb[idx] = (short)cvt_bf16(v);
                } else if (ACT == 8) {
                    Cb[(size_t)m * ldc + n] = (short)cvt_bf16(v);
                }
            }
        }
    }
}

// ---------------------------------------------------------------------------
// K3c: gemm8p — 256x256, BK=64, 8-phase schedule (T3+T4+T5 per guide §5.5):
// 2-deep 128 KB LDS; per half-K-tile 4 phases of {4 ds_read A-quadrant ||
// 2 gload16 stage -> setprio MFMA x16 -> s_barrier}; B frags read once per
// tile; __syncthreads between halves = vmcnt drain for loads issued a full
// half earlier (latency covered). Fragment-ordered LDS (conflict-free, no
// swizzle needed). ACT 5 epilogue (in_proj split).
// ---------------------------------------------------------------------------
__global__ __launch_bounds__(512) void gemm8p(
    const short* __restrict__ A, int lda,
    const short* __restrict__ Wt, int ldw,
    short* __restrict__ Cb, int M, int N, int K)
{
    extern __shared__ short lds[];            // Ab: 2*16384, Bb: 2*16384
    short* Ab = lds;
    short* Bb = lds + 32768;
    int tid  = threadIdx.x;
    int lane = tid & 63, wv = tid >> 6;
    int wm = wv >> 2, wn = wv & 3;            // 2 x 4
    int n0 = blockIdx.x * 256;
    int m0 = blockIdx.y * 256;

    int r = lane & 15, g = lane >> 4;
    // wave stages rowgroups s = wv*2, wv*2+1 for both operands
    const short* aSrc0 = A  + (size_t)(m0 + wv * 32 + r) * lda + g * 8;
    const short* aSrc1 = aSrc0 + (size_t)16 * lda;
    const short* bSrc0 = Wt + (size_t)(n0 + wv * 32 + r) * ldw + g * 8;
    const short* bSrc1 = bSrc0 + (size_t)16 * ldw;

    f32x4 acc[8][4];
    #pragma unroll
    for (int i = 0; i < 8; ++i)
        #pragma unroll
        for (int j = 0; j < 4; ++j) {
            acc[i][j][0] = 0.f; acc[i][j][1] = 0.f;
            acc[i][j][2] = 0.f; acc[i][j][3] = 0.f;
        }

    // LDS subtile (rowgroup s, khalf kk) lives at (s*2+kk)*512 shorts.
    #define LDA2(bufR, i0)                                                      \
        _Pragma("unroll") for (int ii = 0; ii < 2; ++ii)                        \
          _Pragma("unroll") for (int kk = 0; kk < 2; ++kk)                      \
            af[ii][kk] = *(const bf16x8*)&Ab[(bufR) * 16384 +                   \
                ((wm * 8 + (i0) + ii) * 2 + kk) * 512 + lane * 8];

    #define MM2(i0)                                                            \
        __builtin_amdgcn_s_setprio(1);                                         \
        _Pragma("unroll") for (int ii = 0; ii < 2; ++ii)                       \
          _Pragma("unroll") for (int j = 0; j < 4; ++j)                        \
            _Pragma("unroll") for (int kk = 0; kk < 2; ++kk)                   \
              acc[(i0) + ii][j] = __builtin_amdgcn_mfma_f32_16x16x32_bf16(     \
                  af[ii][kk], bfr[j][kk], acc[(i0) + ii][j], 0, 0, 0);         \
        __builtin_amdgcn_s_setprio(0);

    #define HALF(bufR, bufW, ktS, doStage)                                     \
    do {                                                                       \
        const int co = (ktS) * 64;                                             \
        bf16x8 bfr[4][2];                                                      \
        _Pragma("unroll") for (int j = 0; j < 4; ++j)                          \
          _Pragma("unroll") for (int kk = 0; kk < 2; ++kk)                     \
            bfr[j][kk] = *(const bf16x8*)&Bb[(bufR) * 16384 +                  \
                ((wn * 4 + j) * 2 + kk) * 512 + lane * 8];                     \
        bf16x8 af[2][2];                                                       \
        /* phase 0 */                                                          \
        LDA2(bufR, 0)                                                          \
        if (doStage) {                                                         \
            gload16(aSrc0 + co,      &Ab[(bufW) * 16384 + (wv * 4 + 0) * 512]);\
            gload16(aSrc0 + co + 32, &Ab[(bufW) * 16384 + (wv * 4 + 1) * 512]);\
        }                                                                      \
        MM2(0)                                                                 \
        __builtin_amdgcn_s_barrier();                                          \
        /* phase 1 */                                                          \
        LDA2(bufR, 2)                                                          \
        if (doStage) {                                                         \
            gload16(aSrc1 + co,      &Ab[(bufW) * 16384 + (wv * 4 + 2) * 512]);\
            gload16(aSrc1 + co + 32, &Ab[(bufW) * 16384 + (wv * 4 + 3) * 512]);\
        }                                                                      \
        MM2(2)                                                                 \
        __builtin_amdgcn_s_barrier();                                          \
        /* phase 2 */                                                          \
        LDA2(bufR, 4)                                                          \
        if (doStage) {                                                         \
            gload16(bSrc0 + co,      &Bb[(bufW) * 16384 + (wv * 4 + 0) * 512]);\
            gload16(bSrc0 + co + 32, &Bb[(bufW) * 16384 + (wv * 4 + 1) * 512]);\
        }                                                                      \
        MM2(4)                                                                 \
        __builtin_amdgcn_s_barrier();                                          \
        /* phase 3 */                                                          \
        LDA2(bufR, 6)                                                          \
        if (doStage) {                                                         \
            gload16(bSrc1 + co,      &Bb[(bufW) * 16384 + (wv * 4 + 2) * 512]);\
            gload16(bSrc1 + co + 32, &Bb[(bufW) * 16384 + (wv * 4 + 3) * 512]);\
        }                                                                      \
        MM2(6)                                                                 \
    } while (0)

    int T64 = K >> 6;                         // K-tiles of 64 (in_proj: 16)
    // prologue: stage tile 0 -> buf0 (8 loads)
    gload16(aSrc0 + 0,  &Ab[(wv * 4 + 0) * 512]);
    gload16(aSrc0 + 32, &Ab[(wv * 4 + 1) * 512]);
    gload16(aSrc1 + 0,  &Ab[(wv * 4 + 2) * 512]);
    gload16(aSrc1 + 32, &Ab[(wv * 4 + 3) * 512]);
    gload16(bSrc0 + 0,  &Bb[(wv * 4 + 0) * 512]);
    gload16(bSrc0 + 32, &Bb[(wv * 4 + 1) * 512]);
    gload16(bSrc1 + 0,  &Bb[(wv * 4 + 2) * 512]);
    gload16(bSrc1 + 32, &Bb[(wv * 4 + 3) * 512]);
    __syncthreads();                          // tile 0 landed (vmcnt drain)

    #pragma unroll 1
    for (int it = 0; it < (T64 >> 1); ++it) {
        // compute tile 2it (buf0); stage tile 2it+1 -> buf1
        HALF(0, 1, 2 * it + 1, true);
        __syncthreads();                      // tile 2it+1 landed
        // compute tile 2it+1 (buf1); stage tile 2it+2 -> buf0
        if (2 * it + 2 < T64) {
            HALF(1, 0, 2 * it + 2, true);
            __syncthreads();                  // tile 2it+2 landed
        } else {
            HALF(1, 0, 0, false);
        }
    }
    #undef HALF
    #undef MM2
    #undef LDA2

    // epilogue: ACT 5 in_proj split (xmb | zb contiguous arena)
    #pragma unroll
    for (int i = 0; i < 8; ++i) {
        int mb = m0 + wm * 128 + i * 16 + ((lane >> 4) << 2);
        #pragma unroll
        for (int j = 0; j < 4; ++j) {
            int n = n0 + wn * 64 + j * 16 + (lane & 15);
            #pragma unroll
            for (int rr = 0; rr < 4; ++rr) {
                int m = mb + rr;
                float v = acc[i][j][rr];
                size_t idx = (n < DI_) ? ((size_t)m * DI_ + n)
                                       : ((size_t)ROWS * DI_ + (size_t)m * DI_ + (n - DI_));
                Cb[idx] = (short)cvt_bf16(v);
            }
        }
    }
}

// ---------------------------------------------------------------------------
// Reduce kernels
// ---------------------------------------------------------------------------
__global__ __launch_bounds__(256) void redk_xproj(
    const float* __restrict__ part, float* __restrict__ dbl,
    short* __restrict__ dblb)
{
    size_t i = ((size_t)blockIdx.x * 256 + threadIdx.x) * 4;
    const size_t seg = (size_t)ROWS * 96;
    float4 s = *(const float4*)(part + i);
    #pragma unroll
    for (int z = 1; z < 8; ++z) {
        float4 p = *(const float4*)(part + z * seg + i);
        s.x += p.x; s.y += p.y; s.z += p.z; s.w += p.w;
    }
    *(float4*)(dbl + i) = s;
    uint2 p = { pack_bf16_2(s.x, s.y), pack_bf16_2(s.z, s.w) };
    *(uint2*)(dblb + i) = p;
}

// hgd1/fr reduce: sum 2 f32 segs + bias + silu, split -> h1b / frlin
__global__ __launch_bounds__(256) void redk_hgdfr(
    const float* __restrict__ part, const float* __restrict__ hgd_b1,
    const float* __restrict__ fr_b, short* __restrict__ h1b,
    short* __restrict__ frlin)
{
    size_t i = ((size_t)blockIdx.x * 256 + threadIdx.x) * 4;   // over ROWS*512
    const size_t seg = (size_t)ROWS * 512;
    int m   = (int)(i >> 9);
    int col = (int)(i & 511);
    float4 a = *(const float4*)(part + i);
    float4 b = *(const float4*)(part + seg + i);
    float s0 = a.x + b.x, s1 = a.y + b.y, s2 = a.z + b.z, s3 = a.w + b.w;
    const float* bias = (col < 256) ? (hgd_b1 + col) : (fr_b + col - 256);
    float4 bv = *(const float4*)bias;
    float o0 = silu_f(s0 + bv.x), o1 = silu_f(s1 + bv.y);
    float o2 = silu_f(s2 + bv.z), o3 = silu_f(s3 + bv.w);
    uint2 p = { pack_bf16_2(o0, o1), pack_bf16_2(o2, o3) };
    short* dst = (col < 256) ? (h1b + (size_t)m * 256 + col)
                             : (frlin + (size_t)m * 256 + col - 256);
    *(uint2*)dst = p;
}

// out_proj reduce (bf16 partials): x12b = bf16(sum of 4)
__global__ __launch_bounds__(256) void redk_op4(
    const short* __restrict__ part, short* __restrict__ x12b)
{
    size_t i = ((size_t)blockIdx.x * 256 + threadIdx.x) * 8;
    const size_t seg = (size_t)ROWS * H_;
    float s[8];
    bf16x8 p0 = *(const bf16x8*)(part + i);
    #pragma unroll
    for (int e = 0; e < 8; ++e) s[e] = bf16_to_f((unsigned short)p0[e]);
    #pragma unroll
    for (int z = 1; z < 4; ++z) {
        bf16x8 pz = *(const bf16x8*)(part + z * seg + i);
        #pragma unroll
        for (int e = 0; e < 8; ++e) s[e] += bf16_to_f((unsigned short)pz[e]);
    }
    bf16x8 o;
    #pragma unroll
    for (int e = 0; e < 8; ++e) o[e] = (short)cvt_bf16(s[e]);
    *(bf16x8*)(x12b + i) = o;
}

// fm reduce: a = silu(sum4 + fm_b), ab = a * frlin -> abb bf16
__global__ __launch_bounds__(256) void redk_fm(
    const float* __restrict__ part, const float* __restrict__ fm_b,
    const short* __restrict__ frlin, short* __restrict__ abb)
{
    size_t i = ((size_t)blockIdx.x * 256 + threadIdx.x) * 4;
    const size_t seg = (size_t)ROWS * HR_;
    float4 s = *(const float4*)(part + i);
    #pragma unroll
    for (int z = 1; z < 4; ++z) {
        float4 p = *(const float4*)(part + z * seg + i);
        s.x += p.x; s.y += p.y; s.z += p.z; s.w += p.w;
    }
    int col = (int)(i & (HR_ - 1));
    float4 b = *(const float4*)(fm_b + col);
    const short* fr = frlin + i;
    float o0 = silu_f(s.x + b.x) * bf16_to_f((unsigned short)fr[0]);
    float o1 = silu_f(s.y + b.y) * bf16_to_f((unsigned short)fr[1]);
    float o2 = silu_f(s.z + b.z) * bf16_to_f((unsigned short)fr[2]);
    float o3 = silu_f(s.w + b.w) * bf16_to_f((unsigned short)fr[3]);
    uint2 p = { pack_bf16_2(o0, o1), pack_bf16_2(o2, o3) };
    *(uint2*)(abb + i) = p;
}

// ---------------------------------------------------------------------------
// K4: depthwise causal conv + bias + silu, register sliding window.
// ---------------------------------------------------------------------------
__global__ __launch_bounds__(256) void conv_kernel(
    const short* __restrict__ xmb, const float* __restrict__ cwt,
    const float* __restrict__ conv_b, short* __restrict__ xcb)
{
    int d0 = threadIdx.x * 8;
    int b  = blockIdx.y;
    int l0 = blockIdx.x * CLT_;

    float w[KC_][8];
    #pragma unroll
    for (int j = 0; j < KC_; ++j) {
        float4 a = *(const float4*)&cwt[j * DI_ + d0];
        float4 c = *(const float4*)&cwt[j * DI_ + d0 + 4];
        w[j][0] = a.x; w[j][1] = a.y; w[j][2] = a.z; w[j][3] = a.w;
        w[j][4] = c.x; w[j][5] = c.y; w[j][6] = c.z; w[j][7] = c.w;
    }
    float bia[8];
    {
        float4 b0 = *(const float4*)&conv_b[d0];
        float4 b1 = *(const float4*)&conv_b[d0 + 4];
        bia[0] = b0.x; bia[1] = b0.y; bia[2] = b0.z; bia[3] = b0.w;
        bia[4] = b1.x; bia[5] = b1.y; bia[6] = b1.z; bia[7] = b1.w;
    }

    const short* base = xmb + (size_t)b * L_ * DI_ + d0;
    short*       outb = xcb + (size_t)b * L_ * DI_ + d0;

    bf16x8 win[KC_];
    #pragma unroll
    for (int j = 0; j < KC_ - 1; ++j) {
        int ll = l0 - (KC_ - 1) + j;
        if (ll >= 0) win[j] = *(const bf16x8*)(base + (size_t)ll * DI_);
        else         win[j] = (bf16x8)0;
    }
    for (int l = l0; l < l0 + CLT_; ++l) {
        win[KC_ - 1] = *(const bf16x8*)(base + (size_t)l * DI_);
        bf16x8 o;
        #pragma unroll
        for (int e = 0; e < 8; ++e) {
            float acc = bia[e];
            #pragma unroll
            for (int j = 0; j < KC_; ++j)
                acc = fmaf(bf16_to_f((unsigned short)win[j][e]), w[j][e], acc);
            o[e] = (short)cvt_bf16(silu_f(acc));
        }
        *(bf16x8*)(outb + (size_t)l * DI_) = o;
        win[0] = win[1]; win[1] = win[2]; win[2] = win[3];
    }
}

// ---------------------------------------------------------------------------
// K5a: chunked scan phase 1, NS-split, double-buffered LDS staging.
// Grid B*NCH*16 = 2048 blocks.
// ---------------------------------------------------------------------------
__global__ __launch_bounds__(256) void scan_part1(
    const short* __restrict__ dtb, const short* __restrict__ xcb,
    const float* __restrict__ dbl, const float* __restrict__ A_log,
    float* __restrict__ hend, float* __restrict__ dtsum)
{
    int bx = blockIdx.x;
    int dg = bx & 15;
    int bc = bx >> 4;
    int c  = bc & (NCH_ - 1);
    int b  = bc >> 5;
    int tid  = threadIdx.x;
    int lane = tid & 63, wv = tid >> 6;
    int dl   = tid >> 1;
    int d    = dg * 128 + dl;
    int half = tid & 1;
    int n0   = half * 8;

    __shared__ float sB[CL_][NS_];
    __shared__ short dtS[2][16][128];
    __shared__ short xcS[2][16][128];

    size_t srcoff = (size_t)(b * L_ + c * CL_ + wv * 4 + (lane >> 4)) * DI_
                    + dg * 128 + (lane & 15) * 8;
    const short* gdt = dtb + srcoff;
    const short* gxc = xcb + srcoff;

    #define SSTG1(buf, q)                                             \
        do {                                                          \
            gload16(gdt + (size_t)(q) * 16 * DI_, &dtS[buf][wv*4][0]); \
            gload16(gxc + (size_t)(q) * 16 * DI_, &xcS[buf][wv*4][0]); \
        } while (0)

    SSTG1(0, 0);
    for (int idx = tid; idx < CL_ * NS_; idx += 256) {
        int l = idx >> 4, n = idx & 15;
        sB[l][n] = dbl[(size_t)(b * L_ + c * CL_ + l) * 96 + DTR_ + n];
    }
    float Aa2[8];
    #pragma unroll
    for (int n = 0; n < 8; ++n)
        Aa2[n] = -__expf(A_log[d * NS_ + n0 + n]) * LOG2E;

    float h[8];
    #pragma unroll
    for (int n = 0; n < 8; ++n) h[n] = 0.f;
    float sdt = 0.f;

    __syncthreads();
    int buf = 0;
    for (int q = 0; q < 2; ++q) {
        if (q < 1) SSTG1(buf ^ 1, q + 1);
        #pragma unroll
        for (int li = 0; li < 16; ++li) {
            int l = q * 16 + li;
            float dtv = bf16_to_f((unsigned short)dtS[buf][li][dl]);
            float xv  = bf16_to_f((unsigned short)xcS[buf][li][dl]);
            float du  = dtv * xv;
            sdt += dtv;
            #pragma unroll
            for (int n = 0; n < 8; ++n)
                h[n] = fmaf(EXP2(dtv * Aa2[n]), h[n], du * sB[l][n0 + n]);
        }
        __syncthreads();
        buf ^= 1;
    }
    #undef SSTG1

    #pragma unroll
    for (int n = 0; n < 8; ++n)
        hend[((size_t)((b * NCH_ + c) * NS_ + n0 + n)) * DI_ + d] = h[n];
    if (half == 0)
        dtsum[(size_t)(b * NCH_ + c) * DI_ + d] = sdt;
}

// ---------------------------------------------------------------------------
// K5m: serial chunk combine (32 steps), exp2-folded.
// ---------------------------------------------------------------------------
__global__ __launch_bounds__(256) void scan_mid(
    const float* __restrict__ hend, const float* __restrict__ dtsum,
    const float* __restrict__ A_log, float* __restrict__ hin)
{
    int idx = blockIdx.x * 256 + threadIdx.x;
    int d  = idx & (DI_ - 1);
    int bn = idx >> 11;
    int n  = bn & (NS_ - 1);
    int b  = bn >> 4;
    float Aa2 = -__expf(A_log[d * NS_ + n]) * LOG2E;
    float h = 0.f;
    #pragma unroll
    for (int c = 0; c < NCH_; ++c) {
        size_t o = ((size_t)((b * NCH_ + c) * NS_ + n)) * DI_ + d;
        hin[o] = h;
        float s = dtsum[(size_t)(b * NCH_ + c) * DI_ + d];
        h = fmaf(EXP2(Aa2 * s), h, hend[o]);
    }
}

// ---------------------------------------------------------------------------
// K5b: chunked scan phase 2, double-buffered + fused epilogue. 2048 blocks.
// ---------------------------------------------------------------------------
__global__ __launch_bounds__(256) void scan_part2(
    const short* __restrict__ dtb, const short* __restrict__ xcb,
    const short* __restrict__ zb, const float* __restrict__ dbl,
    const float* __restrict__ A_log, const float* __restrict__ Dp,
    const float* __restrict__ hin, short* __restrict__ y2b)
{
    int bx = blockIdx.x;
    int dg = bx & 15;
    int bc = bx >> 4;
    int c  = bc & (NCH_ - 1);
    int b  = bc >> 5;
    int tid  = threadIdx.x;
    int lane = tid & 63, wv = tid >> 6;
    int dl   = tid >> 1;
    int d    = dg * 128 + dl;
    int half = tid & 1;
    int n0   = half * 8;

    __shared__ float sBC[CL_][2 * NS_];
    __shared__ short dtS[2][16][128];
    __shared__ short xcS[2][16][128];
    __shared__ short zS[2][16][128];

    size_t srcoff = (size_t)(b * L_ + c * CL_ + wv * 4 + (lane >> 4)) * DI_
                    + dg * 128 + (lane & 15) * 8;
    const short* gdt = dtb + srcoff;
    const short* gxc = xcb + srcoff;
    const short* gz  = zb  + srcoff;

    #define SSTG2(buf, q)                                             \
        do {                                                          \
            gload16(gdt + (size_t)(q) * 16 * DI_, &dtS[buf][wv*4][0]); \
            gload16(gxc + (size_t)(q) * 16 * DI_, &xcS[buf][wv*4][0]); \
            gload16(gz  + (size_t)(q) * 16 * DI_, &zS[buf][wv*4][0]);  \
        } while (0)

    SSTG2(0, 0);
    for (int idx = tid; idx < CL_ * 2 * NS_; idx += 256) {
        int l = idx >> 5, n = idx & 31;
        sBC[l][n] = dbl[(size_t)(b * L_ + c * CL_ + l) * 96 + DTR_ + n];
    }
    float Aa2[8];
    #pragma unroll
    for (int n = 0; n < 8; ++n)
        Aa2[n] = -__expf(A_log[d * NS_ + n0 + n]) * LOG2E;

    float h[8];
    #pragma unroll
    for (int n = 0; n < 8; ++n)
        h[n] = hin[((size_t)((b * NCH_ + c) * NS_ + n0 + n)) * DI_ + d];
    float Dpv = Dp[d];
    size_t obase = (size_t)(b * L_ + c * CL_) * DI_ + d;

    __syncthreads();
    int buf = 0;
    for (int q = 0; q < 2; ++q) {
        if (q < 1) SSTG2(buf ^ 1, q + 1);
        #pragma unroll
        for (int li = 0; li < 16; ++li) {
            int l = q * 16 + li;
            float dtv = bf16_to_f((unsigned short)dtS[buf][li][dl]);
            float xv  = bf16_to_f((unsigned short)xcS[buf][li][dl]);
            float zv  = bf16_to_f((unsigned short)zS[buf][li][dl]);
            float du  = dtv * xv;
            float y = 0.f;
            #pragma unroll
            for (int n = 0; n < 8; ++n) {
                float dA = EXP2(dtv * Aa2[n]);
                h[n] = fmaf(dA, h[n], du * sBC[l][n0 + n]);
                y = fmaf(h[n], sBC[l][NS_ + n0 + n], y);
            }
            y += __shfl_xor(y, 1);
            if (half == 0) {
                y = fmaf(xv, Dpv, y);
                y2b[obase + (size_t)l * DI_] = (short)cvt_bf16(y * silu_f(zv));
            }
        }
        __syncthreads();
        buf ^= 1;
    }
    #undef SSTG2
}

// ---------------------------------------------------------------------------
// launcher
// ---------------------------------------------------------------------------
extern "C" void kernel_launch(void* const* d_in, const int* in_sizes, int n_in,
                              void* d_out, int out_size, void* d_ws, size_t ws_size,
                              hipStream_t stream)
{
    const float* x         = (const float*)d_in[0];
    const float* t         = (const float*)d_in[1];
    const float* ada_w     = (const float*)d_in[2];
    const float* ada_b     = (const float*)d_in[3];
    const float* hgd_w1    = (const float*)d_in[4];
    const float* hgd_b1    = (const float*)d_in[5];
    const float* hgd_w2    = (const float*)d_in[6];
    const float* hgd_b2    = (const float*)d_in[7];
    const float* in_proj_w = (const float*)d_in[8];
    const float* conv_w    = (const float*)d_in[9];
    const float* conv_b    = (const float*)d_in[10];
    const float* x_proj_w  = (const float*)d_in[11];
    const float* dt_proj_w = (const float*)d_in[12];
    const float* dt_proj_b = (const float*)d_in[13];
    const float* A_log     = (const float*)d_in[14];
    const float* Dp        = (const float*)d_in[15];
    const float* out_proj_w= (const float*)d_in[16];
    const float* fm_w      = (const float*)d_in[17];
    const float* fm_b      = (const float*)d_in[18];
    const float* fr_w      = (const float*)d_in[19];
    const float* fr_b      = (const float*)d_in[20];
    const float* ff_w      = (const float*)d_in[21];
    const float* ff_b      = (const float*)d_in[22];
    float* out = (float*)d_out;

    char* p = (char*)d_ws;
    auto alloc = [&](size_t bytes) { char* r = p; p += (bytes + 255) & ~255ull; return r; };

    short* wt      = (short*)alloc(TWT * 2);                    // 16 MB
    float* cwt     = (float*)alloc((size_t)KC_ * DI_ * 4);      // 32 KB
    short* x1b     = (short*)alloc((size_t)ROWS * H_ * 2);      // 8 MB
    short* h1b     = (short*)alloc((size_t)ROWS * HR_ * 2);     // 2 MB
    short* frlin   = (short*)alloc((size_t)ROWS * HR_ * 2);     // 2 MB
    short* xdb     = (short*)alloc((size_t)ROWS * H_ * 2);      // 8 MB
    short* xmzb    = (short*)alloc((size_t)ROWS * DI_ * 4);     // 32 MB: xmb | zb
    short* xcb     = (short*)alloc((size_t)ROWS * DI_ * 2);     // 16 MB
    short* y2b     = (short*)alloc((size_t)ROWS * DI_ * 2);     // 16 MB
    short* dtb     = (short*)alloc((size_t)ROWS * DI_ * 2);     // 16 MB
    float* scratch = (float*)alloc((size_t)4 * ROWS * H_ * 4);  // 67 MB time-shared
    float* dbl     = (float*)alloc((size_t)ROWS * 96 * 4);      // 1.5 MB
    short* dblb    = (short*)alloc((size_t)ROWS * 96 * 2);      // 0.75 MB
    short* x12b    = (short*)alloc((size_t)ROWS * H_ * 2);      // 8 MB
    short* abb     = (short*)alloc((size_t)ROWS * HR_ * 2);     // 2 MB (dtsum overlay)
    float* ada     = (float*)alloc((size_t)B_ * H3_ * 4);

    short* xmb   = xmzb;
    short* zb    = xmzb + (size_t)ROWS * DI_;
    float* dtsum = (float*)abb;                         // 1 MB, dead before abb
    float* adapart = scratch;                           // 1.5 MB
    float* hfpart  = scratch;                           // 16.8 MB (hgd1/fr partials)
    float* xppart  = scratch;                           // 12.6 MB
    float* hend    = scratch;                           // 16.8 MB (after redk_xproj)
    float* hin     = scratch + (size_t)B_ * NCH_ * NS_ * DI_;  // +16.8 MB
    short* oppart  = (short*)scratch;                   // 33.6 MB bf16 (after scan)
    float* fmpart  = scratch;                           // 16.8 MB (after redk_op4)

    dim3 blk(256), b512(512);

    wtrans_kernel<<<dim3(7808), blk, 0, stream>>>(
        hgd_w1, fr_w, hgd_w2, in_proj_w, x_proj_w, dt_proj_w, out_proj_w,
        fm_w, ff_w, wt);
    cwt_kernel<<<dim3(DI_ / 256), blk, 0, stream>>>(conv_w, cwt);
    ada_part_kernel<<<dim3(3, B_, 32), blk, 0, stream>>>(t, ada_w, adapart);
    ada_red_kernel<<<dim3(B_ * H3_ / 4 / 256), blk, 0, stream>>>(adapart, ada_b, ada);
    ln_mod_kernel<<<dim3(ROWS), blk, 0, stream>>>(x, ada, x1b);
    // hgd1/fr partials  N=512 K=1024 splitK=2 (slice 512) -> f32 scratch
    gemm128<0, true><<<dim3(4, 32, 2), blk, 0, stream>>>(
        x1b, H_, wt + TW_HGDFR, H_, nullptr, hfpart, nullptr, nullptr,
        512, ROWS, 512, 512, nullptr, nullptr);
    redk_hgdfr<<<dim3(ROWS * 512 / 4 / 256), blk, 0, stream>>>(
        hfpart, hgd_b1, fr_b, h1b, frlin);
    // xd = h1 @ hgd_w2 + b2 -> bf16   N=1024 K=256
    gemm128<0, false><<<dim3(8, 32), blk, 0, stream>>>(
        h1b, HR_, wt + TW_HGD2, HR_, hgd_b2, nullptr, xdb, nullptr,
        H_, ROWS, H_, HR_, nullptr, nullptr);
    // xz = xd @ in_proj_w -> xmb|zb bf16   N=4096 K=1024  (8-phase 256² BK=64)
    gemm8p<<<dim3(16, 16), b512, 131072, stream>>>(
        xdb, H_, wt + TW_INPJ, H_, xmb, ROWS, 2 * DI_, H_);
    // conv + silu -> xcb bf16
    conv_kernel<<<dim3(L_ / CLT_, B_), blk, 0, stream>>>(xmb, cwt, conv_b, xcb);
    // dbl partials = xc @ x_proj_w  (splitK=8, slice 256)
    gemm128<0, true><<<dim3(1, 32, 8), blk, 0, stream>>>(
        xcb, DI_, wt + TW_XPJ, DI_, nullptr, xppart, nullptr, nullptr,
        96, ROWS, 96, 256, nullptr, nullptr);
    redk_xproj<<<dim3(ROWS * 96 / 4 / 256), blk, 0, stream>>>(xppart, dbl, dblb);
    // dt = softplus(dbl[:, :64] @ dt_proj_w + dt_proj_b) -> bf16  N=2048 K=64
    gemm128<2, false><<<dim3(16, 32), blk, 0, stream>>>(
        dblb, 96, wt + TW_DTPJ, DTR_, dt_proj_b, nullptr, dtb, nullptr,
        DI_, ROWS, DI_, DTR_, nullptr, nullptr);
    // chunked scan
    scan_part1<<<dim3(B_ * NCH_ * 16), blk, 0, stream>>>(
        dtb, xcb, dbl, A_log, hend, dtsum);
    scan_mid<<<dim3(B_ * DI_ * NS_ / 256), blk, 0, stream>>>(
        hend, dtsum, A_log, hin);
    scan_part2<<<dim3(B_ * NCH_ * 16), blk, 0, stream>>>(
        dtb, xcb, zb, dbl, A_log, Dp, hin, y2b);
    // x1_2 partials = y2 @ out_proj_w  (proven 3-buf 256² splitK=4, bf16 partials)
    gemm256<8, true><<<dim3(4, 16, 4), b512, 98304, stream>>>(
        y2b, DI_, wt + TW_OPJ, DI_, oppart, H_, ROWS, H_, 512);
    redk_op4<<<dim3(ROWS * H_ / 8 / 256), blk, 0, stream>>>(oppart, x12b);
    // fm partials = x1_2 @ fm_w  (splitK=4, slice 256)
    gemm128<0, true><<<dim3(2, 32, 4), blk, 0, stream>>>(
        x12b, H_, wt + TW_FM, H_, nullptr, fmpart, nullptr, nullptr,
        HR_, ROWS, HR_, 256, nullptr, nullptr);
    // ab = silu(sum + fm_b) * frlin -> abb
    redk_fm<<<dim3(ROWS * HR_ / 4 / 256), blk, 0, stream>>>(fmpart, fm_b, frlin, abb);
    // out = x + alpha * (ab @ ff_w + ff_b)   N=1024 K=256
    gemm128<4, false><<<dim3(8, 32), blk, 0, stream>>>(
        abb, HR_, wt + TW_FF, HR_, ff_b, out, nullptr, nullptr,
        H_, ROWS, H_, HR_, x, ada);
}

// Round 21
// 327.581 us; speedup vs baseline: 1.3917x; 1.3917x over previous
//
#include <hip/hip_runtime.h>
#include <math.h>
#include <stdint.h>

#define H_   1024
#define HR_  256
#define DI_  2048
#define NS_  16
#define KC_  4
#define DTR_ 64
#define B_   4
#define L_   1024
#define ROWS (B_*L_)   // 4096
#define H3_  3072
#define NCH_ 32        // scan chunks
#define CL_  32        // chunk length
#define CLT_ 8         // conv rows per thread

typedef short bf16x8 __attribute__((ext_vector_type(8)));
typedef float f32x4  __attribute__((ext_vector_type(4)));

#if __has_builtin(__builtin_amdgcn_exp2f)
#define EXP2(x) __builtin_amdgcn_exp2f(x)
#else
#define EXP2(x) __expf((x) * 0.6931471805599453f)
#endif
#define LOG2E 1.4426950408889634f

__device__ __forceinline__ float silu_f(float v) { return v / (1.f + __expf(-v)); }

__device__ __forceinline__ uint32_t pack_bf16_2(float a, float b) {
    uint32_t ua = __float_as_uint(a);
    uint32_t ub = __float_as_uint(b);
    uint32_t ra = (ua + 0x7FFFu + ((ua >> 16) & 1u)) >> 16;
    uint32_t rb = (ub + 0x7FFFu + ((ub >> 16) & 1u)) >> 16;
    return ra | (rb << 16);
}
__device__ __forceinline__ unsigned short cvt_bf16(float a) {
    uint32_t ua = __float_as_uint(a);
    return (unsigned short)((ua + 0x7FFFu + ((ua >> 16) & 1u)) >> 16);
}
__device__ __forceinline__ float bf16_to_f(unsigned short u) {
    return __uint_as_float(((uint32_t)u) << 16);
}

// async global->LDS, 16B per lane: LDS dest = wave-uniform base + lane*16
__device__ __forceinline__ void gload16(const short* g, short* l) {
    __builtin_amdgcn_global_load_lds(
        (const __attribute__((address_space(1))) void*)g,
        (__attribute__((address_space(3))) void*)l, 16, 0, 0);
}

// ---------------------------------------------------------------------------
// Transposed bf16 weight arena offsets (shorts). Wt layout: [Npad][K]
// ---------------------------------------------------------------------------
#define TW_HGDFR 0ull        // [512][1024]: rows 0-255 hgd_w1, 256-511 fr_w
#define TW_HGD2  524288ull   // [1024][256]
#define TW_INPJ  786432ull   // [4096][1024]
#define TW_XPJ   4980736ull  // [128][2048] (zero-padded from 96)
#define TW_DTPJ  5242880ull  // [2048][64]
#define TW_OPJ   5373952ull  // [1024][2048]
#define TW_FM    7471104ull  // [256][1024]
#define TW_FF    7733248ull  // [1024][256]
#define TWT      7995392ull

// ---------------------------------------------------------------------------
// K0: transpose+convert weights: W[K][N] f32 -> Wt[Npad][K] bf16
// ---------------------------------------------------------------------------
__global__ __launch_bounds__(256) void wtrans_kernel(
    const float* __restrict__ s0, const float* __restrict__ s1,
    const float* __restrict__ s2, const float* __restrict__ s3,
    const float* __restrict__ s4, const float* __restrict__ s5,
    const float* __restrict__ s6, const float* __restrict__ s7,
    const float* __restrict__ s8, short* __restrict__ wt)
{
    int bid = blockIdx.x;
    const float* src; short* dst; int K, N, rel;
    if      (bid < 256)  { src = s0; dst = wt + TW_HGDFR;          K = 1024; N = 256;  rel = bid; }
    else if (bid < 512)  { src = s1; dst = wt + TW_HGDFR + 262144; K = 1024; N = 256;  rel = bid - 256; }
    else if (bid < 768)  { src = s2; dst = wt + TW_HGD2;           K = 256;  N = 1024; rel = bid - 512; }
    else if (bid < 4864) { src = s3; dst = wt + TW_INPJ;           K = 1024; N = 4096; rel = bid - 768; }
    else if (bid < 5120) { src = s4; dst = wt + TW_XPJ;            K = 2048; N = 96;   rel = bid - 4864; }
    else if (bid < 5248) { src = s5; dst = wt + TW_DTPJ;           K = 64;   N = 2048; rel = bid - 5120; }
    else if (bid < 7296) { src = s6; dst = wt + TW_OPJ;            K = 2048; N = 1024; rel = bid - 5248; }
    else if (bid < 7552) { src = s7; dst = wt + TW_FM;             K = 1024; N = 256;  rel = bid - 7296; }
    else                 { src = s8; dst = wt + TW_FF;             K = 256;  N = 1024; rel = bid - 7552; }
    int tkc = K >> 5;
    int tk = rel % tkc, tn = rel / tkc;

    __shared__ float ld[32][33];
    int tx = threadIdx.x & 7, ty = threadIdx.x >> 3;
    int kk = tk * 32 + ty, nn = tn * 32 + tx * 4;
    float4 v = make_float4(0.f, 0.f, 0.f, 0.f);
    if (nn < N) v = *(const float4*)&src[(size_t)kk * N + nn];
    ld[ty][tx * 4 + 0] = v.x; ld[ty][tx * 4 + 1] = v.y;
    ld[ty][tx * 4 + 2] = v.z; ld[ty][tx * 4 + 3] = v.w;
    __syncthreads();
    int nn2 = tn * 32 + ty, kk2 = tk * 32 + tx * 4;
    float a0 = ld[tx * 4 + 0][ty], a1 = ld[tx * 4 + 1][ty];
    float a2 = ld[tx * 4 + 2][ty], a3 = ld[tx * 4 + 3][ty];
    uint2 p = { pack_bf16_2(a0, a1), pack_bf16_2(a2, a3) };
    *(uint2*)&dst[(size_t)nn2 * K + kk2] = p;
}

// ---------------------------------------------------------------------------
// K0b: conv weight transpose
// ---------------------------------------------------------------------------
__global__ __launch_bounds__(256) void cwt_kernel(
    const float* __restrict__ conv_w, float* __restrict__ cwt)
{
    int d = blockIdx.x * 256 + threadIdx.x;
    float4 v = *(const float4*)&conv_w[d * KC_];
    cwt[0 * DI_ + d] = v.x;
    cwt[1 * DI_ + d] = v.y;
    cwt[2 * DI_ + d] = v.z;
    cwt[3 * DI_ + d] = v.w;
}

// ---------------------------------------------------------------------------
// K1a/b: ada = silu(t) @ ada_w + ada_b  (splitK=32)
// ---------------------------------------------------------------------------
__global__ __launch_bounds__(256) void ada_part_kernel(
    const float* __restrict__ t, const float* __restrict__ ada_w,
    float* __restrict__ part)
{
    int col = blockIdx.x * 1024 + threadIdx.x * 4;
    int b = blockIdx.y, z = blockIdx.z;
    __shared__ float st[32];
    if (threadIdx.x < 32) {
        float v = t[b * H_ + z * 32 + threadIdx.x];
        st[threadIdx.x] = silu_f(v);
    }
    __syncthreads();
    float4 acc = make_float4(0.f, 0.f, 0.f, 0.f);
    const float* w = ada_w + (size_t)(z * 32) * H3_ + col;
    #pragma unroll
    for (int k = 0; k < 32; ++k) {
        float4 wv = *(const float4*)(w + (size_t)k * H3_);
        float s = st[k];
        acc.x = fmaf(s, wv.x, acc.x);
        acc.y = fmaf(s, wv.y, acc.y);
        acc.z = fmaf(s, wv.z, acc.z);
        acc.w = fmaf(s, wv.w, acc.w);
    }
    *(float4*)&part[((size_t)z * B_ + b) * H3_ + col] = acc;
}

__global__ __launch_bounds__(256) void ada_red_kernel(
    const float* __restrict__ part, const float* __restrict__ ada_b,
    float* __restrict__ ada)
{
    int i = (blockIdx.x * 256 + threadIdx.x) * 4;
    int b = i / H3_, col = i - b * H3_;
    float4 s = make_float4(0.f, 0.f, 0.f, 0.f);
    #pragma unroll
    for (int z = 0; z < 32; ++z) {
        float4 p = *(const float4*)&part[((size_t)z * B_ + b) * H3_ + col];
        s.x += p.x; s.y += p.y; s.z += p.z; s.w += p.w;
    }
    float4 bv = *(const float4*)&ada_b[col];
    s.x += bv.x; s.y += bv.y; s.z += bv.z; s.w += bv.w;
    *(float4*)&ada[(size_t)b * H3_ + col] = s;
}

// ---------------------------------------------------------------------------
// K2: x1 = LN(x) * (1+scale) + shift  -> bf16
// ---------------------------------------------------------------------------
__global__ __launch_bounds__(256) void ln_mod_kernel(
    const float* __restrict__ x, const float* __restrict__ ada,
    short* __restrict__ x1b)
{
    int row = blockIdx.x;
    int b   = row >> 10;
    const float* xr = x + (size_t)row * H_;
    float4 v = ((const float4*)xr)[threadIdx.x];
    float s  = v.x + v.y + v.z + v.w;
    float s2 = v.x*v.x + v.y*v.y + v.z*v.z + v.w*v.w;

    __shared__ float red[8];
    int wave = threadIdx.x >> 6, lane = threadIdx.x & 63;
    #pragma unroll
    for (int off = 32; off; off >>= 1) {
        s  += __shfl_down(s,  off);
        s2 += __shfl_down(s2, off);
    }
    if (lane == 0) { red[wave] = s; red[4 + wave] = s2; }
    __syncthreads();
    float ts  = red[0] + red[1] + red[2] + red[3];
    float ts2 = red[4] + red[5] + red[6] + red[7];
    float mu  = ts  * (1.f / H_);
    float var = ts2 * (1.f / H_) - mu * mu;
    float inv = rsqrtf(var + 1e-6f);

    const float* sh = ada + b * H3_;
    int i = threadIdx.x * 4;
    float4 sh4 = *(const float4*)&sh[i];
    float4 sc4 = *(const float4*)&sh[H_ + i];
    float ox = (v.x - mu) * inv * (1.f + sc4.x) + sh4.x;
    float oy = (v.y - mu) * inv * (1.f + sc4.y) + sh4.y;
    float oz = (v.z - mu) * inv * (1.f + sc4.z) + sh4.z;
    float ow = (v.w - mu) * inv * (1.f + sc4.w) + sh4.w;
    uint2 p = { pack_bf16_2(ox, oy), pack_bf16_2(oz, ow) };
    *(uint2*)(x1b + (size_t)row * H_ + i) = p;
}

// ---------------------------------------------------------------------------
// K3a: gemm128 — 128x128, BK=32, 4 waves, 3-buf counted vmcnt.
// ACT: 0 none, 2 softplus->Cb, 4 E0+alpha*v->C, 6 hgd1|fr split
// ---------------------------------------------------------------------------
template<int ACT, bool SPLITK>
__global__ __launch_bounds__(256) void gemm128(
    const short* __restrict__ A, int lda,
    const short* __restrict__ Wt, int ldw,
    const float* __restrict__ bias,
    float* __restrict__ C, short* __restrict__ Cb, short* __restrict__ Cb2,
    int ldc, int M, int N, int K,
    const float* __restrict__ E0, const float* __restrict__ E1)
{
    __shared__ short As[3][4096];
    __shared__ short Bs[3][4096];
    int tid  = threadIdx.x;
    int lane = tid & 63, wv = tid >> 6, wm = wv >> 1, wn = wv & 1;
    int n0 = blockIdx.x * 128;
    int m0 = blockIdx.y * 128;

    if (SPLITK) {
        int z = blockIdx.z;
        A  += (size_t)z * K;
        Wt += (size_t)z * K;
        C  += (size_t)z * M * N;
    }

    int r = lane & 15, g = lane >> 4;
    int sA = wv * 2;
    const short* ga0 = A  + (size_t)(m0 + sA * 16 + r) * lda + g * 8;
    const short* ga1 = ga0 + (size_t)16 * lda;
    const short* gb0 = Wt + (size_t)(n0 + sA * 16 + r) * ldw + g * 8;
    const short* gb1 = gb0 + (size_t)16 * ldw;

    f32x4 acc[4][4];
    #pragma unroll
    for (int i = 0; i < 4; ++i)
        #pragma unroll
        for (int j = 0; j < 4; ++j) {
            acc[i][j][0] = 0.f; acc[i][j][1] = 0.f;
            acc[i][j][2] = 0.f; acc[i][j][3] = 0.f;
        }

    #define STAGE(buf, koff)                                    \
        do {                                                    \
            gload16(ga0 + (koff), &As[buf][sA * 512]);          \
            gload16(ga1 + (koff), &As[buf][sA * 512 + 512]);    \
            gload16(gb0 + (koff), &Bs[buf][sA * 512]);          \
            gload16(gb1 + (koff), &Bs[buf][sA * 512 + 512]);    \
        } while (0)

    #define COMPUTE(buf)                                                          \
        do {                                                                      \
            bf16x8 af[4], bfr[4];                                                 \
            _Pragma("unroll")                                                     \
            for (int i = 0; i < 4; ++i)                                           \
                af[i] = *(const bf16x8*)&As[buf][(wm * 4 + i) * 512 + lane * 8];  \
            _Pragma("unroll")                                                     \
            for (int j = 0; j < 4; ++j)                                           \
                bfr[j] = *(const bf16x8*)&Bs[buf][(wn * 4 + j) * 512 + lane * 8]; \
            _Pragma("unroll")                                                     \
            for (int i = 0; i < 4; ++i)                                           \
                _Pragma("unroll")                                                 \
                for (int j = 0; j < 4; ++j)                                       \
                    acc[i][j] = __builtin_amdgcn_mfma_f32_16x16x32_bf16(          \
                        af[i], bfr[j], acc[i][j], 0, 0, 0);                       \
        } while (0)

    int T = K >> 5;
    STAGE(0, 0);
    if (T > 1) STAGE(1, 32);
    for (int t = 0; t < T; ++t) {
        if (t + 1 < T) asm volatile("s_waitcnt vmcnt(4)" ::: "memory");
        else           asm volatile("s_waitcnt vmcnt(0)" ::: "memory");
        __builtin_amdgcn_s_barrier();
        if (t + 2 < T) STAGE((t + 2) % 3, (t + 2) * 32);
        COMPUTE(t % 3);
    }
    #undef STAGE
    #undef COMPUTE

    #pragma unroll
    for (int i = 0; i < 4; ++i) {
        int mb = m0 + wm * 64 + i * 16 + ((lane >> 4) << 2);
        #pragma unroll
        for (int j = 0; j < 4; ++j) {
            int n = n0 + wn * 64 + j * 16 + (lane & 15);
            if (n < N) {
                float bv;
                if (ACT == 6) bv = (n < 256) ? bias[n] : E0[n - 256];
                else          bv = bias ? bias[n] : 0.f;
                #pragma unroll
                for (int rr = 0; rr < 4; ++rr) {
                    int m = mb + rr;
                    float v = acc[i][j][rr] + bv;
                    size_t ci = (size_t)m * ldc + n;
                    if (ACT == 6) {
                        float sv = silu_f(v);
                        if (n < 256) Cb[(size_t)m * 256 + n]        = (short)cvt_bf16(sv);
                        else         Cb2[(size_t)m * 256 + (n-256)] = (short)cvt_bf16(sv);
                    } else {
                        if (ACT == 2) v = (v > 20.f) ? v : log1pf(__expf(v));
                        else if (ACT == 4) {
                            int bb = m >> 10;
                            v = E0[ci] + E1[bb * H3_ + 2 * H_ + n] * v;
                        }
                        if (C)  C[ci]  = v;
                        if (Cb) Cb[ci] = (short)cvt_bf16(v);
                    }
                }
            }
        }
    }
}

// ---------------------------------------------------------------------------
// K3b: gemm256 — 256x256, BK=32, 8 waves, 3-buf counted vmcnt, 96 KB LDS.
// ACT: 5 in_proj split -> Cb arena; 8 bf16 splitK partials -> Cb + z*M*N
// ---------------------------------------------------------------------------
template<int ACT, bool SPLITK>
__global__ __launch_bounds__(512) void gemm256(
    const short* __restrict__ A, int lda,
    const short* __restrict__ Wt, int ldw,
    short* __restrict__ Cb, int ldc, int M, int N, int K)
{
    extern __shared__ short lds[];            // As: 3*8192, Bs: 3*8192
    short* Asb = lds;
    short* Bsb = lds + 24576;
    int tid  = threadIdx.x;
    int lane = tid & 63, wv = tid >> 6;
    int wm = wv >> 2, wn = wv & 3;
    int n0 = blockIdx.x * 256;
    int m0 = blockIdx.y * 256;

    if (SPLITK) {
        int z = blockIdx.z;
        A  += (size_t)z * K;
        Wt += (size_t)z * K;
        Cb += (size_t)z * M * N;
    }

    int r = lane & 15, g = lane >> 4;
    int sA = wv * 2;
    const short* ga0 = A  + (size_t)(m0 + sA * 16 + r) * lda + g * 8;
    const short* ga1 = ga0 + (size_t)16 * lda;
    const short* gb0 = Wt + (size_t)(n0 + sA * 16 + r) * ldw + g * 8;
    const short* gb1 = gb0 + (size_t)16 * ldw;

    f32x4 acc[8][4];
    #pragma unroll
    for (int i = 0; i < 8; ++i)
        #pragma unroll
        for (int j = 0; j < 4; ++j) {
            acc[i][j][0] = 0.f; acc[i][j][1] = 0.f;
            acc[i][j][2] = 0.f; acc[i][j][3] = 0.f;
        }

    #define STAGE2(buf, koff)                                       \
        do {                                                        \
            gload16(ga0 + (koff), &Asb[(buf) * 8192 + sA * 512]);   \
            gload16(ga1 + (koff), &Asb[(buf) * 8192 + sA * 512 + 512]); \
            gload16(gb0 + (koff), &Bsb[(buf) * 8192 + sA * 512]);   \
            gload16(gb1 + (koff), &Bsb[(buf) * 8192 + sA * 512 + 512]); \
        } while (0)

    int T = K >> 5;
    STAGE2(0, 0);
    if (T > 1) STAGE2(1, 32);
    for (int t = 0; t < T; ++t) {
        if (t + 1 < T) asm volatile("s_waitcnt vmcnt(4)" ::: "memory");
        else           asm volatile("s_waitcnt vmcnt(0)" ::: "memory");
        __builtin_amdgcn_s_barrier();
        if (t + 2 < T) STAGE2((t + 2) % 3, (t + 2) * 32);
        {
            int buf = t % 3;
            bf16x8 af[8], bfr[4];
            #pragma unroll
            for (int i = 0; i < 8; ++i)
                af[i] = *(const bf16x8*)&Asb[buf * 8192 + (wm * 8 + i) * 512 + lane * 8];
            #pragma unroll
            for (int j = 0; j < 4; ++j)
                bfr[j] = *(const bf16x8*)&Bsb[buf * 8192 + (wn * 4 + j) * 512 + lane * 8];
            __builtin_amdgcn_s_setprio(1);
            #pragma unroll
            for (int i = 0; i < 8; ++i)
                #pragma unroll
                for (int j = 0; j < 4; ++j)
                    acc[i][j] = __builtin_amdgcn_mfma_f32_16x16x32_bf16(
                        af[i], bfr[j], acc[i][j], 0, 0, 0);
            __builtin_amdgcn_s_setprio(0);
        }
    }
    #undef STAGE2

    #pragma unroll
    for (int i = 0; i < 8; ++i) {
        int mb = m0 + wm * 128 + i * 16 + ((lane >> 4) << 2);
        #pragma unroll
        for (int j = 0; j < 4; ++j) {
            int n = n0 + wn * 64 + j * 16 + (lane & 15);
            #pragma unroll
            for (int rr = 0; rr < 4; ++rr) {
                int m = mb + rr;
                float v = acc[i][j][rr];
                if (ACT == 5) {
                    size_t idx = (n < DI_) ? ((size_t)m * DI_ + n)
                                           : ((size_t)ROWS * DI_ + (size_t)m * DI_ + (n - DI_));
                    Cb[idx] = (short)cvt_bf16(v);
                } else if (ACT == 8) {
                    Cb[(size_t)m * ldc + n] = (short)cvt_bf16(v);
                }
            }
        }
    }
}

// ---------------------------------------------------------------------------
// Reduce kernels
// ---------------------------------------------------------------------------
__global__ __launch_bounds__(256) void redk_xproj(
    const float* __restrict__ part, float* __restrict__ dbl,
    short* __restrict__ dblb)
{
    size_t i = ((size_t)blockIdx.x * 256 + threadIdx.x) * 4;
    const size_t seg = (size_t)ROWS * 96;
    float4 s = *(const float4*)(part + i);
    #pragma unroll
    for (int z = 1; z < 8; ++z) {
        float4 p = *(const float4*)(part + z * seg + i);
        s.x += p.x; s.y += p.y; s.z += p.z; s.w += p.w;
    }
    *(float4*)(dbl + i) = s;
    uint2 p = { pack_bf16_2(s.x, s.y), pack_bf16_2(s.z, s.w) };
    *(uint2*)(dblb + i) = p;
}

// hgd1/fr reduce: sum 2 f32 segs + bias + silu, split -> h1b / frlin
__global__ __launch_bounds__(256) void redk_hgdfr(
    const float* __restrict__ part, const float* __restrict__ hgd_b1,
    const float* __restrict__ fr_b, short* __restrict__ h1b,
    short* __restrict__ frlin)
{
    size_t i = ((size_t)blockIdx.x * 256 + threadIdx.x) * 4;   // over ROWS*512
    const size_t seg = (size_t)ROWS * 512;
    int m   = (int)(i >> 9);
    int col = (int)(i & 511);
    float4 a = *(const float4*)(part + i);
    float4 b = *(const float4*)(part + seg + i);
    float s0 = a.x + b.x, s1 = a.y + b.y, s2 = a.z + b.z, s3 = a.w + b.w;
    const float* bias = (col < 256) ? (hgd_b1 + col) : (fr_b + col - 256);
    float4 bv = *(const float4*)bias;
    float o0 = silu_f(s0 + bv.x), o1 = silu_f(s1 + bv.y);
    float o2 = silu_f(s2 + bv.z), o3 = silu_f(s3 + bv.w);
    uint2 p = { pack_bf16_2(o0, o1), pack_bf16_2(o2, o3) };
    short* dst = (col < 256) ? (h1b + (size_t)m * 256 + col)
                             : (frlin + (size_t)m * 256 + col - 256);
    *(uint2*)dst = p;
}

// out_proj reduce (bf16 partials): x12b = bf16(sum of 4)
__global__ __launch_bounds__(256) void redk_op4(
    const short* __restrict__ part, short* __restrict__ x12b)
{
    size_t i = ((size_t)blockIdx.x * 256 + threadIdx.x) * 8;
    const size_t seg = (size_t)ROWS * H_;
    float s[8];
    bf16x8 p0 = *(const bf16x8*)(part + i);
    #pragma unroll
    for (int e = 0; e < 8; ++e) s[e] = bf16_to_f((unsigned short)p0[e]);
    #pragma unroll
    for (int z = 1; z < 4; ++z) {
        bf16x8 pz = *(const bf16x8*)(part + z * seg + i);
        #pragma unroll
        for (int e = 0; e < 8; ++e) s[e] += bf16_to_f((unsigned short)pz[e]);
    }
    bf16x8 o;
    #pragma unroll
    for (int e = 0; e < 8; ++e) o[e] = (short)cvt_bf16(s[e]);
    *(bf16x8*)(x12b + i) = o;
}

// fm reduce: a = silu(sum4 + fm_b), ab = a * frlin -> abb bf16
__global__ __launch_bounds__(256) void redk_fm(
    const float* __restrict__ part, const float* __restrict__ fm_b,
    const short* __restrict__ frlin, short* __restrict__ abb)
{
    size_t i = ((size_t)blockIdx.x * 256 + threadIdx.x) * 4;
    const size_t seg = (size_t)ROWS * HR_;
    float4 s = *(const float4*)(part + i);
    #pragma unroll
    for (int z = 1; z < 4; ++z) {
        float4 p = *(const float4*)(part + z * seg + i);
        s.x += p.x; s.y += p.y; s.z += p.z; s.w += p.w;
    }
    int col = (int)(i & (HR_ - 1));
    float4 b = *(const float4*)(fm_b + col);
    const short* fr = frlin + i;
    float o0 = silu_f(s.x + b.x) * bf16_to_f((unsigned short)fr[0]);
    float o1 = silu_f(s.y + b.y) * bf16_to_f((unsigned short)fr[1]);
    float o2 = silu_f(s.z + b.z) * bf16_to_f((unsigned short)fr[2]);
    float o3 = silu_f(s.w + b.w) * bf16_to_f((unsigned short)fr[3]);
    uint2 p = { pack_bf16_2(o0, o1), pack_bf16_2(o2, o3) };
    *(uint2*)(abb + i) = p;
}

// ---------------------------------------------------------------------------
// K4: depthwise causal conv + bias + silu, register sliding window.
// ---------------------------------------------------------------------------
__global__ __launch_bounds__(256) void conv_kernel(
    const short* __restrict__ xmb, const float* __restrict__ cwt,
    const float* __restrict__ conv_b, short* __restrict__ xcb)
{
    int d0 = threadIdx.x * 8;
    int b  = blockIdx.y;
    int l0 = blockIdx.x * CLT_;

    float w[KC_][8];
    #pragma unroll
    for (int j = 0; j < KC_; ++j) {
        float4 a = *(const float4*)&cwt[j * DI_ + d0];
        float4 c = *(const float4*)&cwt[j * DI_ + d0 + 4];
        w[j][0] = a.x; w[j][1] = a.y; w[j][2] = a.z; w[j][3] = a.w;
        w[j][4] = c.x; w[j][5] = c.y; w[j][6] = c.z; w[j][7] = c.w;
    }
    float bia[8];
    {
        float4 b0 = *(const float4*)&conv_b[d0];
        float4 b1 = *(const float4*)&conv_b[d0 + 4];
        bia[0] = b0.x; bia[1] = b0.y; bia[2] = b0.z; bia[3] = b0.w;
        bia[4] = b1.x; bia[5] = b1.y; bia[6] = b1.z; bia[7] = b1.w;
    }

    const short* base = xmb + (size_t)b * L_ * DI_ + d0;
    short*       outb = xcb + (size_t)b * L_ * DI_ + d0;

    bf16x8 win[KC_];
    #pragma unroll
    for (int j = 0; j < KC_ - 1; ++j) {
        int ll = l0 - (KC_ - 1) + j;
        if (ll >= 0) win[j] = *(const bf16x8*)(base + (size_t)ll * DI_);
        else         win[j] = (bf16x8)0;
    }
    for (int l = l0; l < l0 + CLT_; ++l) {
        win[KC_ - 1] = *(const bf16x8*)(base + (size_t)l * DI_);
        bf16x8 o;
        #pragma unroll
        for (int e = 0; e < 8; ++e) {
            float acc = bia[e];
            #pragma unroll
            for (int j = 0; j < KC_; ++j)
                acc = fmaf(bf16_to_f((unsigned short)win[j][e]), w[j][e], acc);
            o[e] = (short)cvt_bf16(silu_f(acc));
        }
        *(bf16x8*)(outb + (size_t)l * DI_) = o;
        win[0] = win[1]; win[1] = win[2]; win[2] = win[3];
    }
}

// ---------------------------------------------------------------------------
// K5a: chunked scan phase 1, NS-split, double-buffered LDS staging.
// Grid B*NCH*16 = 2048 blocks.
// ---------------------------------------------------------------------------
__global__ __launch_bounds__(256) void scan_part1(
    const short* __restrict__ dtb, const short* __restrict__ xcb,
    const float* __restrict__ dbl, const float* __restrict__ A_log,
    float* __restrict__ hend, float* __restrict__ dtsum)
{
    int bx = blockIdx.x;
    int dg = bx & 15;
    int bc = bx >> 4;
    int c  = bc & (NCH_ - 1);
    int b  = bc >> 5;
    int tid  = threadIdx.x;
    int lane = tid & 63, wv = tid >> 6;
    int dl   = tid >> 1;
    int d    = dg * 128 + dl;
    int half = tid & 1;
    int n0   = half * 8;

    __shared__ float sB[CL_][NS_];
    __shared__ short dtS[2][16][128];
    __shared__ short xcS[2][16][128];

    size_t srcoff = (size_t)(b * L_ + c * CL_ + wv * 4 + (lane >> 4)) * DI_
                    + dg * 128 + (lane & 15) * 8;
    const short* gdt = dtb + srcoff;
    const short* gxc = xcb + srcoff;

    #define SSTG1(buf, q)                                             \
        do {                                                          \
            gload16(gdt + (size_t)(q) * 16 * DI_, &dtS[buf][wv*4][0]); \
            gload16(gxc + (size_t)(q) * 16 * DI_, &xcS[buf][wv*4][0]); \
        } while (0)

    SSTG1(0, 0);
    for (int idx = tid; idx < CL_ * NS_; idx += 256) {
        int l = idx >> 4, n = idx & 15;
        sB[l][n] = dbl[(size_t)(b * L_ + c * CL_ + l) * 96 + DTR_ + n];
    }
    float Aa2[8];
    #pragma unroll
    for (int n = 0; n < 8; ++n)
        Aa2[n] = -__expf(A_log[d * NS_ + n0 + n]) * LOG2E;

    float h[8];
    #pragma unroll
    for (int n = 0; n < 8; ++n) h[n] = 0.f;
    float sdt = 0.f;

    __syncthreads();
    int buf = 0;
    for (int q = 0; q < 2; ++q) {
        if (q < 1) SSTG1(buf ^ 1, q + 1);
        #pragma unroll
        for (int li = 0; li < 16; ++li) {
            int l = q * 16 + li;
            float dtv = bf16_to_f((unsigned short)dtS[buf][li][dl]);
            float xv  = bf16_to_f((unsigned short)xcS[buf][li][dl]);
            float du  = dtv * xv;
            sdt += dtv;
            #pragma unroll
            for (int n = 0; n < 8; ++n)
                h[n] = fmaf(EXP2(dtv * Aa2[n]), h[n], du * sB[l][n0 + n]);
        }
        __syncthreads();
        buf ^= 1;
    }
    #undef SSTG1

    #pragma unroll
    for (int n = 0; n < 8; ++n)
        hend[((size_t)((b * NCH_ + c) * NS_ + n0 + n)) * DI_ + d] = h[n];
    if (half == 0)
        dtsum[(size_t)(b * NCH_ + c) * DI_ + d] = sdt;
}

// ---------------------------------------------------------------------------
// K5m: serial chunk combine (32 steps), exp2-folded.
// ---------------------------------------------------------------------------
__global__ __launch_bounds__(256) void scan_mid(
    const float* __restrict__ hend, const float* __restrict__ dtsum,
    const float* __restrict__ A_log, float* __restrict__ hin)
{
    int idx = blockIdx.x * 256 + threadIdx.x;
    int d  = idx & (DI_ - 1);
    int bn = idx >> 11;
    int n  = bn & (NS_ - 1);
    int b  = bn >> 4;
    float Aa2 = -__expf(A_log[d * NS_ + n]) * LOG2E;
    float h = 0.f;
    #pragma unroll
    for (int c = 0; c < NCH_; ++c) {
        size_t o = ((size_t)((b * NCH_ + c) * NS_ + n)) * DI_ + d;
        hin[o] = h;
        float s = dtsum[(size_t)(b * NCH_ + c) * DI_ + d];
        h = fmaf(EXP2(Aa2 * s), h, hend[o]);
    }
}

// ---------------------------------------------------------------------------
// K5b: chunked scan phase 2, double-buffered + fused epilogue. 2048 blocks.
// ---------------------------------------------------------------------------
__global__ __launch_bounds__(256) void scan_part2(
    const short* __restrict__ dtb, const short* __restrict__ xcb,
    const short* __restrict__ zb, const float* __restrict__ dbl,
    const float* __restrict__ A_log, const float* __restrict__ Dp,
    const float* __restrict__ hin, short* __restrict__ y2b)
{
    int bx = blockIdx.x;
    int dg = bx & 15;
    int bc = bx >> 4;
    int c  = bc & (NCH_ - 1);
    int b  = bc >> 5;
    int tid  = threadIdx.x;
    int lane = tid & 63, wv = tid >> 6;
    int dl   = tid >> 1;
    int d    = dg * 128 + dl;
    int half = tid & 1;
    int n0   = half * 8;

    __shared__ float sBC[CL_][2 * NS_];
    __shared__ short dtS[2][16][128];
    __shared__ short xcS[2][16][128];
    __shared__ short zS[2][16][128];

    size_t srcoff = (size_t)(b * L_ + c * CL_ + wv * 4 + (lane >> 4)) * DI_
                    + dg * 128 + (lane & 15) * 8;
    const short* gdt = dtb + srcoff;
    const short* gxc = xcb + srcoff;
    const short* gz  = zb  + srcoff;

    #define SSTG2(buf, q)                                             \
        do {                                                          \
            gload16(gdt + (size_t)(q) * 16 * DI_, &dtS[buf][wv*4][0]); \
            gload16(gxc + (size_t)(q) * 16 * DI_, &xcS[buf][wv*4][0]); \
            gload16(gz  + (size_t)(q) * 16 * DI_, &zS[buf][wv*4][0]);  \
        } while (0)

    SSTG2(0, 0);
    for (int idx = tid; idx < CL_ * 2 * NS_; idx += 256) {
        int l = idx >> 5, n = idx & 31;
        sBC[l][n] = dbl[(size_t)(b * L_ + c * CL_ + l) * 96 + DTR_ + n];
    }
    float Aa2[8];
    #pragma unroll
    for (int n = 0; n < 8; ++n)
        Aa2[n] = -__expf(A_log[d * NS_ + n0 + n]) * LOG2E;

    float h[8];
    #pragma unroll
    for (int n = 0; n < 8; ++n)
        h[n] = hin[((size_t)((b * NCH_ + c) * NS_ + n0 + n)) * DI_ + d];
    float Dpv = Dp[d];
    size_t obase = (size_t)(b * L_ + c * CL_) * DI_ + d;

    __syncthreads();
    int buf = 0;
    for (int q = 0; q < 2; ++q) {
        if (q < 1) SSTG2(buf ^ 1, q + 1);
        #pragma unroll
        for (int li = 0; li < 16; ++li) {
            int l = q * 16 + li;
            float dtv = bf16_to_f((unsigned short)dtS[buf][li][dl]);
            float xv  = bf16_to_f((unsigned short)xcS[buf][li][dl]);
            float zv  = bf16_to_f((unsigned short)zS[buf][li][dl]);
            float du  = dtv * xv;
            float y = 0.f;
            #pragma unroll
            for (int n = 0; n < 8; ++n) {
                float dA = EXP2(dtv * Aa2[n]);
                h[n] = fmaf(dA, h[n], du * sBC[l][n0 + n]);
                y = fmaf(h[n], sBC[l][NS_ + n0 + n], y);
            }
            y += __shfl_xor(y, 1);
            if (half == 0) {
                y = fmaf(xv, Dpv, y);
                y2b[obase + (size_t)l * DI_] = (short)cvt_bf16(y * silu_f(zv));
            }
        }
        __syncthreads();
        buf ^= 1;
    }
    #undef SSTG2
}

// ---------------------------------------------------------------------------
// launcher
// ---------------------------------------------------------------------------
extern "C" void kernel_launch(void* const* d_in, const int* in_sizes, int n_in,
                              void* d_out, int out_size, void* d_ws, size_t ws_size,
                              hipStream_t stream)
{
    const float* x         = (const float*)d_in[0];
    const float* t         = (const float*)d_in[1];
    const float* ada_w     = (const float*)d_in[2];
    const float* ada_b     = (const float*)d_in[3];
    const float* hgd_w1    = (const float*)d_in[4];
    const float* hgd_b1    = (const float*)d_in[5];
    const float* hgd_w2    = (const float*)d_in[6];
    const float* hgd_b2    = (const float*)d_in[7];
    const float* in_proj_w = (const float*)d_in[8];
    const float* conv_w    = (const float*)d_in[9];
    const float* conv_b    = (const float*)d_in[10];
    const float* x_proj_w  = (const float*)d_in[11];
    const float* dt_proj_w = (const float*)d_in[12];
    const float* dt_proj_b = (const float*)d_in[13];
    const float* A_log     = (const float*)d_in[14];
    const float* Dp        = (const float*)d_in[15];
    const float* out_proj_w= (const float*)d_in[16];
    const float* fm_w      = (const float*)d_in[17];
    const float* fm_b      = (const float*)d_in[18];
    const float* fr_w      = (const float*)d_in[19];
    const float* fr_b      = (const float*)d_in[20];
    const float* ff_w      = (const float*)d_in[21];
    const float* ff_b      = (const float*)d_in[22];
    float* out = (float*)d_out;

    char* p = (char*)d_ws;
    auto alloc = [&](size_t bytes) { char* r = p; p += (bytes + 255) & ~255ull; return r; };

    short* wt      = (short*)alloc(TWT * 2);                    // 16 MB
    float* cwt     = (float*)alloc((size_t)KC_ * DI_ * 4);      // 32 KB
    short* x1b     = (short*)alloc((size_t)ROWS * H_ * 2);      // 8 MB
    short* h1b     = (short*)alloc((size_t)ROWS * HR_ * 2);     // 2 MB
    short* frlin   = (short*)alloc((size_t)ROWS * HR_ * 2);     // 2 MB
    short* xdb     = (short*)alloc((size_t)ROWS * H_ * 2);      // 8 MB
    short* xmzb    = (short*)alloc((size_t)ROWS * DI_ * 4);     // 32 MB: xmb | zb
    short* xcb     = (short*)alloc((size_t)ROWS * DI_ * 2);     // 16 MB
    short* y2b     = (short*)alloc((size_t)ROWS * DI_ * 2);     // 16 MB
    short* dtb     = (short*)alloc((size_t)ROWS * DI_ * 2);     // 16 MB
    float* scratch = (float*)alloc((size_t)4 * ROWS * H_ * 4);  // 67 MB time-shared
    float* dbl     = (float*)alloc((size_t)ROWS * 96 * 4);      // 1.5 MB
    short* dblb    = (short*)alloc((size_t)ROWS * 96 * 2);      // 0.75 MB
    short* x12b    = (short*)alloc((size_t)ROWS * H_ * 2);      // 8 MB
    short* abb     = (short*)alloc((size_t)ROWS * HR_ * 2);     // 2 MB (dtsum overlay)
    float* ada     = (float*)alloc((size_t)B_ * H3_ * 4);

    short* xmb   = xmzb;
    short* zb    = xmzb + (size_t)ROWS * DI_;
    float* dtsum = (float*)abb;                         // 1 MB, dead before abb
    float* adapart = scratch;                           // 1.5 MB
    float* hfpart  = scratch;                           // 16.8 MB (hgd1/fr partials)
    float* xppart  = scratch;                           // 12.6 MB
    float* hend    = scratch;                           // 16.8 MB (after redk_xproj)
    float* hin     = scratch + (size_t)B_ * NCH_ * NS_ * DI_;  // +16.8 MB
    short* oppart  = (short*)scratch;                   // 33.6 MB bf16 (after scan)
    float* fmpart  = scratch;                           // 16.8 MB (after redk_op4)

    dim3 blk(256), b512(512);

    wtrans_kernel<<<dim3(7808), blk, 0, stream>>>(
        hgd_w1, fr_w, hgd_w2, in_proj_w, x_proj_w, dt_proj_w, out_proj_w,
        fm_w, ff_w, wt);
    cwt_kernel<<<dim3(DI_ / 256), blk, 0, stream>>>(conv_w, cwt);
    ada_part_kernel<<<dim3(3, B_, 32), blk, 0, stream>>>(t, ada_w, adapart);
    ada_red_kernel<<<dim3(B_ * H3_ / 4 / 256), blk, 0, stream>>>(adapart, ada_b, ada);
    ln_mod_kernel<<<dim3(ROWS), blk, 0, stream>>>(x, ada, x1b);
    // hgd1/fr partials  N=512 K=1024 splitK=2 (slice 512) -> f32 scratch
    gemm128<0, true><<<dim3(4, 32, 2), blk, 0, stream>>>(
        x1b, H_, wt + TW_HGDFR, H_, nullptr, hfpart, nullptr, nullptr,
        512, ROWS, 512, 512, nullptr, nullptr);
    redk_hgdfr<<<dim3(ROWS * 512 / 4 / 256), blk, 0, stream>>>(
        hfpart, hgd_b1, fr_b, h1b, frlin);
    // xd = h1 @ hgd_w2 + b2 -> bf16   N=1024 K=256
    gemm128<0, false><<<dim3(8, 32), blk, 0, stream>>>(
        h1b, HR_, wt + TW_HGD2, HR_, hgd_b2, nullptr, xdb, nullptr,
        H_, ROWS, H_, HR_, nullptr, nullptr);
    // xz = xd @ in_proj_w -> xmb|zb bf16   N=4096 K=1024  (proven 3-buf 256²)
    gemm256<5, false><<<dim3(16, 16), b512, 98304, stream>>>(
        xdb, H_, wt + TW_INPJ, H_, xmb, 0, ROWS, 2 * DI_, H_);
    // conv + silu -> xcb bf16
    conv_kernel<<<dim3(L_ / CLT_, B_), blk, 0, stream>>>(xmb, cwt, conv_b, xcb);
    // dbl partials = xc @ x_proj_w  (splitK=8, slice 256)
    gemm128<0, true><<<dim3(1, 32, 8), blk, 0, stream>>>(
        xcb, DI_, wt + TW_XPJ, DI_, nullptr, xppart, nullptr, nullptr,
        96, ROWS, 96, 256, nullptr, nullptr);
    redk_xproj<<<dim3(ROWS * 96 / 4 / 256), blk, 0, stream>>>(xppart, dbl, dblb);
    // dt = softplus(dbl[:, :64] @ dt_proj_w + dt_proj_b) -> bf16  N=2048 K=64
    gemm128<2, false><<<dim3(16, 32), blk, 0, stream>>>(
        dblb, 96, wt + TW_DTPJ, DTR_, dt_proj_b, nullptr, dtb, nullptr,
        DI_, ROWS, DI_, DTR_, nullptr, nullptr);
    // chunked scan
    scan_part1<<<dim3(B_ * NCH_ * 16), blk, 0, stream>>>(
        dtb, xcb, dbl, A_log, hend, dtsum);
    scan_mid<<<dim3(B_ * DI_ * NS_ / 256), blk, 0, stream>>>(
        hend, dtsum, A_log, hin);
    scan_part2<<<dim3(B_ * NCH_ * 16), blk, 0, stream>>>(
        dtb, xcb, zb, dbl, A_log, Dp, hin, y2b);
    // x1_2 partials = y2 @ out_proj_w  (proven 3-buf 256² splitK=4, bf16 partials)
    gemm256<8, true><<<dim3(4, 16, 4), b512, 98304, stream>>>(
        y2b, DI_, wt + TW_OPJ, DI_, oppart, H_, ROWS, H_, 512);
    redk_op4<<<dim3(ROWS * H_ / 8 / 256), blk, 0, stream>>>(oppart, x12b);
    // fm partials = x1_2 @ fm_w  (splitK=4, slice 256)
    gemm128<0, true><<<dim3(2, 32, 4), blk, 0, stream>>>(
        x12b, H_, wt + TW_FM, H_, nullptr, fmpart, nullptr, nullptr,
        HR_, ROWS, HR_, 256, nullptr, nullptr);
    // ab = silu(sum + fm_b) * frlin -> abb
    redk_fm<<<dim3(ROWS * HR_ / 4 / 256), blk, 0, stream>>>(fmpart, fm_b, frlin, abb);
    // out = x + alpha * (ab @ ff_w + ff_b)   N=1024 K=256
    gemm128<4, false><<<dim3(8, 32), blk, 0, stream>>>(
        abb, HR_, wt + TW_FF, HR_, ff_b, out, nullptr, nullptr,
        H_, ROWS, H_, HR_, x, ada);
}